// Round 1
// baseline (596.338 us; speedup 1.0000x reference)
//
#include <hip/hip_runtime.h>
#include <hip/hip_bf16.h>
#include <stdint.h>
#include <stddef.h>

// LiteratiQuantLinear: out = x @ (sign(w)*clamp(scales,1e-8))^T
// M=8192 (4x2048), N=4096 (O), K=4096 (C), group=128 along K.
// Strategy: materialize bf16 A and bf16 quantized-B in d_ws, then run the
// m97-structure bf16 MFMA GEMM (128x128 tile, BK=64, global_load_lds w=16,
// XOR-swizzled LDS to keep DMA lane-contiguity AND conflict-free ds_read_b128).

#define M_DIM 8192
#define N_DIM 4096
#define K_DIM 4096
#define BM 128
#define BN 128
#define BK 64

typedef __bf16 bf16x8 __attribute__((ext_vector_type(8)));
typedef __bf16 bf16x4 __attribute__((ext_vector_type(4)));
typedef float f32x4 __attribute__((ext_vector_type(4)));

__device__ __forceinline__ void async_copy16(const void* g, void* l) {
  __builtin_amdgcn_global_load_lds((__attribute__((address_space(1))) void*)g,
                                   (__attribute__((address_space(3))) void*)l,
                                   16, 0, 0);
}

// ---- prep kernel 1: cast x (fp32) -> bf16, 4 elts/thread ----
__global__ void cast_x_kernel(const float* __restrict__ in, __bf16* __restrict__ out) {
  const int i = blockIdx.x * blockDim.x + threadIdx.x;
  const float4 v = ((const float4*)in)[i];
  bf16x4 q;
  q.x = (__bf16)v.x; q.y = (__bf16)v.y; q.z = (__bf16)v.z; q.w = (__bf16)v.w;
  ((bf16x4*)out)[i] = q;
}

// ---- prep kernel 2: w -> sign(w)*max(scale,1e-8) as bf16, 4 elts/thread ----
// 4 consecutive c always share one group of 128.
__global__ void quant_w_kernel(const float* __restrict__ w,
                               const float* __restrict__ scales,
                               __bf16* __restrict__ out) {
  const int i = blockIdx.x * blockDim.x + threadIdx.x;
  const int idx = i << 2;                 // element index into (O,C) flat
  const int o = idx >> 12;                // / 4096
  const int grp = (idx & 4095) >> 7;      // group along C
  const float s = fmaxf(scales[(o << 5) + grp], 1e-8f);
  const float4 v = ((const float4*)w)[i];
  bf16x4 q;
  q.x = (__bf16)((v.x >= 0.0f) ? s : -s);
  q.y = (__bf16)((v.y >= 0.0f) ? s : -s);
  q.z = (__bf16)((v.z >= 0.0f) ? s : -s);
  q.w = (__bf16)((v.w >= 0.0f) ? s : -s);
  ((bf16x4*)out)[i] = q;
}

// ---- GEMM: C[m][n] = sum_k A[m][k] * Bt[n][k] ----
// LDS slot layout (per tile): slot(r, kc) = r*8 + (kc ^ (r&7)); slot = 16 B
// (8 bf16 of k-chunk kc = k/8). Staging call c: lane l -> slot c*64+l, i.e.
// r = c*8 + (l>>3), kc = (l&7) ^ (l>>3) -- wave-uniform base + lane*16 as the
// DMA requires. Fragment read (quad q = l>>4, mr = l&15): slot =
// (mtile+mr)*8 + ((ks*4+q) ^ (mr&7)) -> bank 4*(kc^r) pattern, conflict-free.
template <bool PRECONV>
__global__ __launch_bounds__(256) void literati_gemm(
    const __bf16* __restrict__ Ab, const __bf16* __restrict__ Bb,
    const float* __restrict__ Af, const float* __restrict__ Bf,
    const float* __restrict__ scales, float* __restrict__ C) {
  __shared__ __align__(16) __bf16 As[BM * BK];
  __shared__ __align__(16) __bf16 Bs[BN * BK];

  const int tid = threadIdx.x;
  const int lane = tid & 63;
  const int wave = tid >> 6;
  const int bn0 = blockIdx.x * BN;
  const int bm0 = blockIdx.y * BM;
  const int wm = (wave >> 1) * 64;  // wave's 64x64 sub-tile
  const int wn = (wave & 1) * 64;

  // staging lane decomposition
  const int l3 = lane >> 3;         // 0..7  (row-in-group)
  const int l7 = lane & 7;          // 0..7  (swizzled chunk)
  const int kc_sw = l7 ^ l3;        // global k-chunk this lane fetches

  // fragment lane decomposition
  const int q = lane >> 4;          // quad 0..3
  const int mr = lane & 15;         // row within 16x16 tile
  const int mx = mr & 7;

  const f32x4 zero = {0.f, 0.f, 0.f, 0.f};
  f32x4 acc[4][4];
#pragma unroll
  for (int i = 0; i < 4; ++i)
#pragma unroll
    for (int j = 0; j < 4; ++j) acc[i][j] = zero;

  for (int k0 = 0; k0 < K_DIM; k0 += BK) {
    if constexpr (PRECONV) {
#pragma unroll
      for (int i = 0; i < 4; ++i) {
        const int c = wave * 4 + i;
        const int row = c * 8 + l3;
        async_copy16(Ab + (size_t)(bm0 + row) * K_DIM + k0 + kc_sw * 8,
                     &As[(c * 64 + lane) * 8]);
      }
#pragma unroll
      for (int i = 0; i < 4; ++i) {
        const int c = wave * 4 + i;
        const int row = c * 8 + l3;
        async_copy16(Bb + (size_t)(bn0 + row) * K_DIM + k0 + kc_sw * 8,
                     &Bs[(c * 64 + lane) * 8]);
      }
      asm volatile("s_waitcnt vmcnt(0)" ::: "memory");
    } else {
      // fallback: convert in-kernel (used only if ws_size < 96 MB)
#pragma unroll
      for (int i = 0; i < 4; ++i) {
        const int c = wave * 4 + i;
        const int row = c * 8 + l3;
        const float* src = Af + (size_t)(bm0 + row) * K_DIM + k0 + kc_sw * 8;
        const float4 v0 = ((const float4*)src)[0];
        const float4 v1 = ((const float4*)src)[1];
        bf16x8 o;
        o[0] = (__bf16)v0.x; o[1] = (__bf16)v0.y;
        o[2] = (__bf16)v0.z; o[3] = (__bf16)v0.w;
        o[4] = (__bf16)v1.x; o[5] = (__bf16)v1.y;
        o[6] = (__bf16)v1.z; o[7] = (__bf16)v1.w;
        *(bf16x8*)&As[(c * 64 + lane) * 8] = o;
      }
#pragma unroll
      for (int i = 0; i < 4; ++i) {
        const int c = wave * 4 + i;
        const int row = c * 8 + l3;
        const int gr = bn0 + row;
        const float* src = Bf + (size_t)gr * K_DIM + k0 + kc_sw * 8;
        const float s = fmaxf(scales[(gr << 5) + ((k0 + kc_sw * 8) >> 7)], 1e-8f);
        const float4 v0 = ((const float4*)src)[0];
        const float4 v1 = ((const float4*)src)[1];
        bf16x8 o;
        o[0] = (__bf16)((v0.x >= 0.f) ? s : -s);
        o[1] = (__bf16)((v0.y >= 0.f) ? s : -s);
        o[2] = (__bf16)((v0.z >= 0.f) ? s : -s);
        o[3] = (__bf16)((v0.w >= 0.f) ? s : -s);
        o[4] = (__bf16)((v1.x >= 0.f) ? s : -s);
        o[5] = (__bf16)((v1.y >= 0.f) ? s : -s);
        o[6] = (__bf16)((v1.z >= 0.f) ? s : -s);
        o[7] = (__bf16)((v1.w >= 0.f) ? s : -s);
        *(bf16x8*)&Bs[(c * 64 + lane) * 8] = o;
      }
    }
    __syncthreads();

#pragma unroll
    for (int ks = 0; ks < 2; ++ks) {
      bf16x8 av[4], bv[4];
#pragma unroll
      for (int i = 0; i < 4; ++i) {
        const int slot = (wm + i * 16 + mr) * 8 + ((ks * 4 + q) ^ mx);
        av[i] = *(const bf16x8*)&As[slot * 8];
      }
#pragma unroll
      for (int j = 0; j < 4; ++j) {
        const int slot = (wn + j * 16 + mr) * 8 + ((ks * 4 + q) ^ mx);
        bv[j] = *(const bf16x8*)&Bs[slot * 8];
      }
#pragma unroll
      for (int i = 0; i < 4; ++i)
#pragma unroll
        for (int j = 0; j < 4; ++j)
          acc[i][j] = __builtin_amdgcn_mfma_f32_16x16x32_bf16(av[i], bv[j],
                                                              acc[i][j], 0, 0, 0);
    }
    __syncthreads();
  }

  // epilogue: D lane mapping col = lane&15, row = 4*(lane>>4)+reg (m89/m91)
  const int row0 = q * 4;
#pragma unroll
  for (int i = 0; i < 4; ++i) {
#pragma unroll
    for (int j = 0; j < 4; ++j) {
      const size_t base =
          (size_t)(bm0 + wm + i * 16 + row0) * N_DIM + (bn0 + wn + j * 16 + mr);
#pragma unroll
      for (int r = 0; r < 4; ++r) C[base + (size_t)r * N_DIM] = acc[i][j][r];
    }
  }
}

extern "C" void kernel_launch(void* const* d_in, const int* in_sizes, int n_in,
                              void* d_out, int out_size, void* d_ws, size_t ws_size,
                              hipStream_t stream) {
  const float* x = (const float*)d_in[0];      // (4,2048,4096) fp32
  const float* w = (const float*)d_in[1];      // (4096,4096) fp32
  const float* sc = (const float*)d_in[2];     // (4096,32) fp32
  float* out = (float*)d_out;                  // (4,2048,4096) fp32

  const size_t need = ((size_t)M_DIM + (size_t)N_DIM) * K_DIM * sizeof(__bf16);
  dim3 grid(N_DIM / BN, M_DIM / BM);

  if (ws_size >= need) {
    __bf16* xb = (__bf16*)d_ws;
    __bf16* wb = xb + (size_t)M_DIM * K_DIM;
    cast_x_kernel<<<(M_DIM * K_DIM / 4) / 256, 256, 0, stream>>>(x, xb);
    quant_w_kernel<<<(N_DIM * K_DIM / 4) / 256, 256, 0, stream>>>(w, sc, wb);
    literati_gemm<true><<<grid, 256, 0, stream>>>(xb, wb, nullptr, nullptr,
                                                  nullptr, out);
  } else {
    literati_gemm<false><<<grid, 256, 0, stream>>>(nullptr, nullptr, x, w, sc,
                                                   out);
  }
}

// Round 2
// 527.677 us; speedup vs baseline: 1.1301x; 1.1301x over previous
//
#include <hip/hip_runtime.h>
#include <hip/hip_bf16.h>
#include <stdint.h>
#include <stddef.h>

// LiteratiQuantLinear: out = x @ (sign(w)*clamp(scales,1e-8))^T
// M=8192 (4x2048), N=4096 (O), K=4096 (C), group=128 along K.
// R2: (a) fused wide prep kernel (16 elts/thread); (b) GEMM inner loop moved
// from 16x16x32 to 32x32x16 MFMA (half the MFMA instructions, -17% MFMA-pipe
// cycles, same ds_read count). Staging (global_load_lds w=16 + XOR-swizzled
// LDS) unchanged from the verified R1 kernel.

#define M_DIM 8192
#define N_DIM 4096
#define K_DIM 4096
#define BM 128
#define BN 128
#define BK 64

typedef __bf16 bf16x8 __attribute__((ext_vector_type(8)));
typedef float f32x16 __attribute__((ext_vector_type(16)));

__device__ __forceinline__ void async_copy16(const void* g, void* l) {
  __builtin_amdgcn_global_load_lds((__attribute__((address_space(1))) void*)g,
                                   (__attribute__((address_space(3))) void*)l,
                                   16, 0, 0);
}

// ---- fused prep: cast x -> bf16 AND w -> sign(w)*max(scale,1e-8) bf16 ----
// 16 elements per thread: 4x float4 loads, 2x 16B stores.
#define X_THREADS ((size_t)M_DIM * K_DIM / 16)  // 2M
#define W_THREADS ((size_t)N_DIM * K_DIM / 16)  // 1M
__global__ __launch_bounds__(256) void prep_kernel(
    const float* __restrict__ x, const float* __restrict__ w,
    const float* __restrict__ scales, __bf16* __restrict__ xb,
    __bf16* __restrict__ wb) {
  const size_t t = (size_t)blockIdx.x * blockDim.x + threadIdx.x;
  if (t < X_THREADS) {
    const float4* src = (const float4*)x + t * 4;
    bf16x8* dst = (bf16x8*)xb + t * 2;
#pragma unroll
    for (int h = 0; h < 2; ++h) {
      const float4 v0 = src[h * 2 + 0];
      const float4 v1 = src[h * 2 + 1];
      bf16x8 o;
      o[0] = (__bf16)v0.x; o[1] = (__bf16)v0.y;
      o[2] = (__bf16)v0.z; o[3] = (__bf16)v0.w;
      o[4] = (__bf16)v1.x; o[5] = (__bf16)v1.y;
      o[6] = (__bf16)v1.z; o[7] = (__bf16)v1.w;
      dst[h] = o;
    }
  } else {
    const size_t u = t - X_THREADS;            // 0 .. W_THREADS-1
    const size_t idx = u * 16;                 // flat (O,C) element index
    const int o_ = (int)(idx >> 12);           // / 4096
    const int grp = (int)(idx & 4095) >> 7;    // group of 128 (16 | 128)
    const float s = fmaxf(scales[(o_ << 5) + grp], 1e-8f);
    const float4* src = (const float4*)w + u * 4;
    bf16x8* dst = (bf16x8*)wb + u * 2;
#pragma unroll
    for (int h = 0; h < 2; ++h) {
      const float4 v0 = src[h * 2 + 0];
      const float4 v1 = src[h * 2 + 1];
      bf16x8 q;
      q[0] = (__bf16)((v0.x >= 0.f) ? s : -s);
      q[1] = (__bf16)((v0.y >= 0.f) ? s : -s);
      q[2] = (__bf16)((v0.z >= 0.f) ? s : -s);
      q[3] = (__bf16)((v0.w >= 0.f) ? s : -s);
      q[4] = (__bf16)((v1.x >= 0.f) ? s : -s);
      q[5] = (__bf16)((v1.y >= 0.f) ? s : -s);
      q[6] = (__bf16)((v1.z >= 0.f) ? s : -s);
      q[7] = (__bf16)((v1.w >= 0.f) ? s : -s);
      dst[h] = q;
    }
  }
}

// ---- GEMM: C[m][n] = sum_k A[m][k] * Bt[n][k] ----
// LDS slot layout (per tile): slot(r, kc) = r*8 + (kc ^ (r&7)); slot = 16 B
// (8 bf16 of k-chunk kc = k/8). Staging call c: lane l -> slot c*64+l, i.e.
// r = c*8 + (l>>3), kc = (l&7) ^ (l>>3) -- wave-uniform base + lane*16 as the
// DMA requires.
// Compute: 2x2 of 32x32x16 per wave (64x64 sub-tile). A-frag: m = lane&31,
// k = 8*(lane>>5)+j (gfx950 "8-contiguous-k" pattern, validated for 16x16x32
// in R1). C/D: col = lane&31, row = (reg&3)+8*(reg>>2)+4*(lane>>5) [m74/m101].
template <bool PRECONV>
__global__ __launch_bounds__(256) void literati_gemm(
    const __bf16* __restrict__ Ab, const __bf16* __restrict__ Bb,
    const float* __restrict__ Af, const float* __restrict__ Bf,
    const float* __restrict__ scales, float* __restrict__ C) {
  __shared__ __align__(16) __bf16 As[BM * BK];
  __shared__ __align__(16) __bf16 Bs[BN * BK];

  const int tid = threadIdx.x;
  const int lane = tid & 63;
  const int wave = tid >> 6;
  const int bn0 = blockIdx.x * BN;
  const int bm0 = blockIdx.y * BM;
  const int wm = (wave >> 1) * 64;  // wave's 64x64 sub-tile
  const int wn = (wave & 1) * 64;

  // staging lane decomposition
  const int l3 = lane >> 3;         // 0..7  (row-in-group)
  const int l7 = lane & 7;          // 0..7  (swizzled chunk)
  const int kc_sw = l7 ^ l3;        // global k-chunk this lane fetches

  // fragment lane decomposition (32x32)
  const int m32 = lane & 31;
  const int hl = lane >> 5;         // half 0/1
  const int mx7 = m32 & 7;

  f32x16 acc[2][2];
#pragma unroll
  for (int i = 0; i < 2; ++i)
#pragma unroll
    for (int j = 0; j < 2; ++j)
#pragma unroll
      for (int r = 0; r < 16; ++r) acc[i][j][r] = 0.f;

  for (int k0 = 0; k0 < K_DIM; k0 += BK) {
    if constexpr (PRECONV) {
#pragma unroll
      for (int i = 0; i < 4; ++i) {
        const int c = wave * 4 + i;
        const int row = c * 8 + l3;
        async_copy16(Ab + (size_t)(bm0 + row) * K_DIM + k0 + kc_sw * 8,
                     &As[(c * 64 + lane) * 8]);
      }
#pragma unroll
      for (int i = 0; i < 4; ++i) {
        const int c = wave * 4 + i;
        const int row = c * 8 + l3;
        async_copy16(Bb + (size_t)(bn0 + row) * K_DIM + k0 + kc_sw * 8,
                     &Bs[(c * 64 + lane) * 8]);
      }
      asm volatile("s_waitcnt vmcnt(0)" ::: "memory");
    } else {
      // fallback: convert in-kernel (used only if ws_size too small)
#pragma unroll
      for (int i = 0; i < 4; ++i) {
        const int c = wave * 4 + i;
        const int row = c * 8 + l3;
        const float* src = Af + (size_t)(bm0 + row) * K_DIM + k0 + kc_sw * 8;
        const float4 v0 = ((const float4*)src)[0];
        const float4 v1 = ((const float4*)src)[1];
        bf16x8 o;
        o[0] = (__bf16)v0.x; o[1] = (__bf16)v0.y;
        o[2] = (__bf16)v0.z; o[3] = (__bf16)v0.w;
        o[4] = (__bf16)v1.x; o[5] = (__bf16)v1.y;
        o[6] = (__bf16)v1.z; o[7] = (__bf16)v1.w;
        *(bf16x8*)&As[(c * 64 + lane) * 8] = o;
      }
#pragma unroll
      for (int i = 0; i < 4; ++i) {
        const int c = wave * 4 + i;
        const int row = c * 8 + l3;
        const int gr = bn0 + row;
        const float* src = Bf + (size_t)gr * K_DIM + k0 + kc_sw * 8;
        const float s = fmaxf(scales[(gr << 5) + ((k0 + kc_sw * 8) >> 7)], 1e-8f);
        const float4 v0 = ((const float4*)src)[0];
        const float4 v1 = ((const float4*)src)[1];
        bf16x8 o;
        o[0] = (__bf16)((v0.x >= 0.f) ? s : -s);
        o[1] = (__bf16)((v0.y >= 0.f) ? s : -s);
        o[2] = (__bf16)((v0.z >= 0.f) ? s : -s);
        o[3] = (__bf16)((v0.w >= 0.f) ? s : -s);
        o[4] = (__bf16)((v1.x >= 0.f) ? s : -s);
        o[5] = (__bf16)((v1.y >= 0.f) ? s : -s);
        o[6] = (__bf16)((v1.z >= 0.f) ? s : -s);
        o[7] = (__bf16)((v1.w >= 0.f) ? s : -s);
        *(bf16x8*)&Bs[(c * 64 + lane) * 8] = o;
      }
    }
    __syncthreads();

#pragma unroll
    for (int ks = 0; ks < 4; ++ks) {  // 4 K-steps of 16
      bf16x8 av[2], bv[2];
      const int kc = ks * 2 + hl;     // this lane's 8-elt k-chunk
#pragma unroll
      for (int i = 0; i < 2; ++i) {
        const int slot = (wm + i * 32 + m32) * 8 + (kc ^ mx7);
        av[i] = *(const bf16x8*)&As[slot * 8];
      }
#pragma unroll
      for (int j = 0; j < 2; ++j) {
        const int slot = (wn + j * 32 + m32) * 8 + (kc ^ mx7);
        bv[j] = *(const bf16x8*)&Bs[slot * 8];
      }
#pragma unroll
      for (int i = 0; i < 2; ++i)
#pragma unroll
        for (int j = 0; j < 2; ++j)
          acc[i][j] = __builtin_amdgcn_mfma_f32_32x32x16_bf16(av[i], bv[j],
                                                              acc[i][j], 0, 0, 0);
    }
    __syncthreads();
  }

  // epilogue: D mapping col = lane&31, row = (reg&3)+8*(reg>>2)+4*(lane>>5)
#pragma unroll
  for (int i = 0; i < 2; ++i) {
#pragma unroll
    for (int j = 0; j < 2; ++j) {
      const int col = bn0 + wn + j * 32 + m32;
      const int rbase = bm0 + wm + i * 32 + 4 * hl;
#pragma unroll
      for (int r = 0; r < 16; ++r) {
        const int row = rbase + (r & 3) + 8 * (r >> 2);
        C[(size_t)row * N_DIM + col] = acc[i][j][r];
      }
    }
  }
}

extern "C" void kernel_launch(void* const* d_in, const int* in_sizes, int n_in,
                              void* d_out, int out_size, void* d_ws, size_t ws_size,
                              hipStream_t stream) {
  const float* x = (const float*)d_in[0];      // (4,2048,4096) fp32
  const float* w = (const float*)d_in[1];      // (4096,4096) fp32
  const float* sc = (const float*)d_in[2];     // (4096,32) fp32
  float* out = (float*)d_out;                  // (4,2048,4096) fp32

  const size_t need = ((size_t)M_DIM + (size_t)N_DIM) * K_DIM * sizeof(__bf16);
  dim3 grid(N_DIM / BN, M_DIM / BM);

  if (ws_size >= need) {
    __bf16* xb = (__bf16*)d_ws;
    __bf16* wb = xb + (size_t)M_DIM * K_DIM;
    const size_t total_threads = X_THREADS + W_THREADS;  // 3M
    prep_kernel<<<(int)(total_threads / 256), 256, 0, stream>>>(x, w, sc, xb, wb);
    literati_gemm<true><<<grid, 256, 0, stream>>>(xb, wb, nullptr, nullptr,
                                                  nullptr, out);
  } else {
    literati_gemm<false><<<grid, 256, 0, stream>>>(nullptr, nullptr, x, w, sc,
                                                   out);
  }
}